// Round 1
// 1117.756 us; speedup vs baseline: 1.2612x; 1.2612x over previous
//
#include <hip/hip_runtime.h>
#include <math.h>

#define S_LEN 2048
#define NBATCH 2
#define NHEADS 16
#define HD 64
#define DM 1024
#define NROWS (NBATCH * S_LEN)   // 4096
#define PADW 68                  // padded LDS row stride (words) for attn tiles

typedef __attribute__((ext_vector_type(8))) short bf16x8;
typedef __attribute__((ext_vector_type(4))) float f32x4;
typedef __attribute__((ext_vector_type(4))) unsigned short us4;

// ---------------- bf16 split helpers (round-to-nearest-even) -----------------
__device__ __forceinline__ unsigned short f2bf(float f) {
    unsigned int u = __float_as_uint(f);
    u += 0x7fffu + ((u >> 16) & 1u);
    return (unsigned short)(u >> 16);
}
__device__ __forceinline__ float bf2f(unsigned short h) {
    return __uint_as_float(((unsigned int)h) << 16);
}
__device__ __forceinline__ void split2(float v, unsigned short& h, unsigned short& l) {
    h = f2bf(v);
    l = f2bf(v - bf2f(h));
}

// ---------------- elementwise split (layout-preserving) ----------------------
__global__ __launch_bounds__(256)
void split_kernel(const float* __restrict__ src, unsigned short* __restrict__ hi,
                  unsigned short* __restrict__ lo, int n4) {
    for (long i = (long)blockIdx.x * 256 + threadIdx.x; i < n4; i += (long)gridDim.x * 256) {
        const float4 v = *(const float4*)(src + i * 4);
        unsigned short h0, h1, h2, h3, l0, l1, l2, l3;
        split2(v.x, h0, l0); split2(v.y, h1, l1);
        split2(v.z, h2, l2); split2(v.w, h3, l3);
        us4 H = {h0, h1, h2, h3}, L = {l0, l1, l2, l3};
        *(us4*)(hi + i * 4) = H;
        *(us4*)(lo + i * 4) = L;
    }
}

// ---------------- transpose + split: WT[n][k] = W[k][n] ----------------------
__global__ __launch_bounds__(256)
void wsplit_kernel(const float* __restrict__ W, unsigned short* __restrict__ hi,
                   unsigned short* __restrict__ lo) {
    __shared__ float T[64][65];
    const int c = threadIdx.x & 63, r0 = threadIdx.x >> 6;
    const int n0 = blockIdx.x * 64, k0 = blockIdx.y * 64;
    #pragma unroll
    for (int it = 0; it < 16; ++it) {
        const int r = r0 + it * 4;
        T[r][c] = W[(long)(k0 + r) * DM + n0 + c];
    }
    __syncthreads();
    #pragma unroll
    for (int it = 0; it < 16; ++it) {
        const int r = r0 + it * 4;                  // n-local
        unsigned short h, l;
        split2(T[c][r], h, l);
        hi[(long)(n0 + r) * DM + k0 + c] = h;
        lo[(long)(n0 + r) * DM + k0 + c] = l;
    }
}

// ---------------- bf16x3 MFMA GEMM ------------------------------------------
// C[4096][1024] = A @ B (+bias), A/B pre-split into bf16 hi/lo.
// B given TRANSPOSED: Bh/Bl are [n][k] so A and B tiles stage identically.
// Tile: BM=128 x BN=64, BK=32. 256 threads = 4 waves, each wave owns 64x32
// (4 m-frags x 2 n-frags of 16x16, K-step 32). 3 MFMAs per fp32 product:
// ah*bh + ah*bl + al*bh.
// LDS tiles are [row][32] bf16 with 16B-block XOR swizzle so both ds_write_b128
// (staging) and ds_read_b128 (fragments) are ~2-way (free).
// MODE 0: A = x rows; epilogue bias + RoPE + per-head transposed store (q,k)
// MODE 1: A = x rows; epilogue bias + per-head transposed store (v)
// MODE 2: A = ctx gathered ([bh][s][d] -> row=(n,s), k=(h,d)); plain store (+bo)
#define SWZ(r) ((((r) & 3) ^ (((r) >> 2) & 3)))

template<int MODE>
__global__ __launch_bounds__(256)
void mfma_gemm(const unsigned short* __restrict__ Ah, const unsigned short* __restrict__ Al,
               const unsigned short* __restrict__ Bh, const unsigned short* __restrict__ Bl,
               const float* __restrict__ bias,
               const float* __restrict__ cosp, const float* __restrict__ sinp,
               float* __restrict__ outp)
{
    __shared__ __align__(16) unsigned short LAh[128 * 32];
    __shared__ __align__(16) unsigned short LAl[128 * 32];
    __shared__ __align__(16) unsigned short LBh[64 * 32];
    __shared__ __align__(16) unsigned short LBl[64 * 32];

    const int tid  = threadIdx.x;
    const int lane = tid & 63;
    const int wid  = tid >> 6;
    const int row0 = blockIdx.y * 128;
    const int col0 = blockIdx.x * 64;

    // ---- staging coords (loop-invariant). A: 512 16B-chunks (2 per thread),
    //      B: 256 16B-chunks (1 per thread). chunk c -> row r = c>>2, blk b = c&3.
    long aBase[2]; int aKoff[2]; int aDst[2];
    #pragma unroll
    for (int half = 0; half < 2; ++half) {
        const int c = tid + half * 256;
        const int r = c >> 2, b = c & 3;
        aDst[half] = r * 32 + ((b ^ SWZ(r)) << 3);
        if (MODE < 2) {
            aBase[half] = (long)(row0 + r) * DM + b * 8;
            aKoff[half] = 0;
        } else {
            const int gr = row0 + r;
            aBase[half] = ((long)((gr >> 11) * NHEADS) * S_LEN + (gr & (S_LEN - 1))) * HD;
            aKoff[half] = b * 8;
        }
    }
    const int rB = tid >> 2, bBlk = tid & 3;
    const long bBase = (long)(col0 + rB) * DM + bBlk * 8;
    const int  bDst  = rB * 32 + ((bBlk ^ SWZ(rB)) << 3);

    // ---- fragment LDS offsets (loop-invariant). k-order bijection: k = g*8+e
    //      used identically for A and B frags.
    const int g = lane >> 4, lr = lane & 15;
    const int wr = (wid >> 1) * 64, wc = (wid & 1) * 32;
    int aoff[4], boff[2];
    #pragma unroll
    for (int mt = 0; mt < 4; ++mt) {
        const int rr = wr + mt * 16 + lr;
        aoff[mt] = rr * 32 + ((g ^ SWZ(rr)) << 3);
    }
    #pragma unroll
    for (int nt = 0; nt < 2; ++nt) {
        const int cc = wc + nt * 16 + lr;
        boff[nt] = cc * 32 + ((g ^ SWZ(cc)) << 3);
    }

    f32x4 acc[4][2];
    {
        const f32x4 z = {0.f, 0.f, 0.f, 0.f};
        #pragma unroll
        for (int mt = 0; mt < 4; ++mt)
            #pragma unroll
            for (int nt = 0; nt < 2; ++nt) acc[mt][nt] = z;
    }

    auto asrc_at = [&](int half, int kt) -> long {
        if (MODE < 2) return aBase[half] + kt;
        const int kk = kt + aKoff[half];
        return aBase[half] + (long)(kk >> 6) * (S_LEN * HD) + (kk & 63);
    };

    // prologue: load k-tile 0 into registers
    bf16x8 cA0h = *(const bf16x8*)(Ah + asrc_at(0, 0));
    bf16x8 cA0l = *(const bf16x8*)(Al + asrc_at(0, 0));
    bf16x8 cA1h = *(const bf16x8*)(Ah + asrc_at(1, 0));
    bf16x8 cA1l = *(const bf16x8*)(Al + asrc_at(1, 0));
    bf16x8 cB_h = *(const bf16x8*)(Bh + bBase);
    bf16x8 cB_l = *(const bf16x8*)(Bl + bBase);

    for (int kt = 0; kt < DM; kt += 32) {
        // write current k-tile to LDS (swizzled)
        *(bf16x8*)(LAh + aDst[0]) = cA0h;
        *(bf16x8*)(LAl + aDst[0]) = cA0l;
        *(bf16x8*)(LAh + aDst[1]) = cA1h;
        *(bf16x8*)(LAl + aDst[1]) = cA1l;
        *(bf16x8*)(LBh + bDst) = cB_h;
        *(bf16x8*)(LBl + bDst) = cB_l;
        __syncthreads();

        // prefetch next k-tile (issued early, lands under the MFMAs)
        const int kn = kt + 32;
        if (kn < DM) {
            cA0h = *(const bf16x8*)(Ah + asrc_at(0, kn));
            cA0l = *(const bf16x8*)(Al + asrc_at(0, kn));
            cA1h = *(const bf16x8*)(Ah + asrc_at(1, kn));
            cA1l = *(const bf16x8*)(Al + asrc_at(1, kn));
            cB_h = *(const bf16x8*)(Bh + bBase + kn);
            cB_l = *(const bf16x8*)(Bl + bBase + kn);
        }

        // compute: 24 MFMAs per wave per k-step
        bf16x8 Bfh[2], Bfl[2];
        #pragma unroll
        for (int nt = 0; nt < 2; ++nt) {
            Bfh[nt] = *(const bf16x8*)(LBh + boff[nt]);
            Bfl[nt] = *(const bf16x8*)(LBl + boff[nt]);
        }
        #pragma unroll
        for (int mt = 0; mt < 4; ++mt) {
            const bf16x8 Afh = *(const bf16x8*)(LAh + aoff[mt]);
            const bf16x8 Afl = *(const bf16x8*)(LAl + aoff[mt]);
            #pragma unroll
            for (int nt = 0; nt < 2; ++nt) {
                acc[mt][nt] = __builtin_amdgcn_mfma_f32_16x16x32_bf16(Afh, Bfh[nt], acc[mt][nt], 0, 0, 0);
                acc[mt][nt] = __builtin_amdgcn_mfma_f32_16x16x32_bf16(Afh, Bfl[nt], acc[mt][nt], 0, 0, 0);
                acc[mt][nt] = __builtin_amdgcn_mfma_f32_16x16x32_bf16(Afl, Bfh[nt], acc[mt][nt], 0, 0, 0);
            }
        }
        __syncthreads();
    }

    // ---- epilogue: C/D frag layout (verified): col = lane&15, row = (lane>>4)*4 + reg
    #pragma unroll
    for (int mt = 0; mt < 4; ++mt) {
        #pragma unroll
        for (int nt = 0; nt < 2; ++nt) {
            const int colg = col0 + wc + nt * 16 + lr;
            const float bv = bias[colg];
            #pragma unroll
            for (int j = 0; j < 4; ++j) {
                const int rowg = row0 + wr + mt * 16 + g * 4 + j;
                float v = acc[mt][nt][j] + bv;
                if (MODE == 2) {
                    outp[(long)rowg * DM + colg] = v;
                } else {
                    const int s  = rowg & (S_LEN - 1);
                    const int n  = rowg >> 11;
                    const int h  = colg >> 6;
                    const int dd = colg & 63;
                    float ov = v;
                    if (MODE == 0) {
                        // RoPE pair (2f, 2f+1) lives in adjacent lanes -> shfl_xor(1)
                        const int f = dd >> 1;
                        const float cs = cosp[s * 32 + f];
                        const float sn = sinp[s * 32 + f];
                        const float p  = __shfl_xor(v, 1);
                        ov = (dd & 1) ? (p * sn + v * cs) : (v * cs - p * sn);
                    }
                    outp[((long)(n * NHEADS + h) * S_LEN + s) * HD + dd] = ov;
                }
            }
        }
    }
}

// ---------------- tiled attention (unchanged this round) ---------------------
__global__ __launch_bounds__(256)
void attn_tiled(const float* __restrict__ qT,
                const float* __restrict__ kT,
                const float* __restrict__ vT,
                float* __restrict__ attn,
                float* __restrict__ ctx)
{
    const int bh = blockIdx.x & 31;
    const int qt = 31 - (blockIdx.x >> 5);   // biggest tiles dispatched first
    const int tid = threadIdx.x;
    const int tx = tid & 15, ty = tid >> 4;
    const int c4 = tid & 15, r0 = tid >> 4;  // staging coords

    __shared__ float Qs[64 * PADW];          // Q transposed: [d][qr]
    __shared__ float KVs[64 * PADW];         // K transposed [d][kc]  /  V [kc][d]
    __shared__ float Ps[64 * PADW];          // P transposed: [kc][qr]

    const long qbase = ((long)bh * S_LEN + qt * 64) * HD;

    // stage Q transposed
    #pragma unroll
    for (int it = 0; it < 4; ++it) {
        const int r = r0 + 16 * it;
        const float4 v = *(const float4*)(qT + qbase + (long)r * HD + c4 * 4);
        Qs[(c4 * 4 + 0) * PADW + r] = v.x;
        Qs[(c4 * 4 + 1) * PADW + r] = v.y;
        Qs[(c4 * 4 + 2) * PADW + r] = v.z;
        Qs[(c4 * 4 + 3) * PADW + r] = v.w;
    }

    float m_r[4], l_r[4];
    #pragma unroll
    for (int i = 0; i < 4; ++i) { m_r[i] = -1e30f; l_r[i] = 0.f; }

    __syncthreads();

    // ---------------- pass 1: online row max & sum ----------------
    for (int kt = 0; kt <= qt; ++kt) {
        const long kbase = ((long)bh * S_LEN + kt * 64) * HD;
        #pragma unroll
        for (int it = 0; it < 4; ++it) {
            const int r = r0 + 16 * it;
            const float4 v = *(const float4*)(kT + kbase + (long)r * HD + c4 * 4);
            KVs[(c4 * 4 + 0) * PADW + r] = v.x;
            KVs[(c4 * 4 + 1) * PADW + r] = v.y;
            KVs[(c4 * 4 + 2) * PADW + r] = v.z;
            KVs[(c4 * 4 + 3) * PADW + r] = v.w;
        }
        __syncthreads();

        float acc[4][4] = {};
        #pragma unroll 8
        for (int d = 0; d < 64; ++d) {
            const float4 af = *(const float4*)(Qs + d * PADW + 4 * ty);
            const float4 bf = *(const float4*)(KVs + d * PADW + 4 * tx);
            const float a[4] = {af.x, af.y, af.z, af.w};
            const float b[4] = {bf.x, bf.y, bf.z, bf.w};
            #pragma unroll
            for (int i = 0; i < 4; ++i)
                #pragma unroll
                for (int j = 0; j < 4; ++j)
                    acc[i][j] += a[i] * b[j];
        }

        const bool diag = (kt == qt);
        #pragma unroll
        for (int i = 0; i < 4; ++i) {
            float tmax = -1e30f;
            #pragma unroll
            for (int j = 0; j < 4; ++j) {
                float s = acc[i][j] * 0.125f;
                if (diag && (4 * tx + j) > (4 * ty + i)) s = -1e30f;
                acc[i][j] = s;
                tmax = fmaxf(tmax, s);
            }
            #pragma unroll
            for (int off = 1; off < 16; off <<= 1)
                tmax = fmaxf(tmax, __shfl_xor(tmax, off));
            const float m_new = fmaxf(m_r[i], tmax);
            float psum = 0.f;
            #pragma unroll
            for (int j = 0; j < 4; ++j)
                psum += __expf(acc[i][j] - m_new);
            #pragma unroll
            for (int off = 1; off < 16; off <<= 1)
                psum += __shfl_xor(psum, off);
            l_r[i] = l_r[i] * __expf(m_r[i] - m_new) + psum;
            m_r[i] = m_new;
        }
        __syncthreads();   // before next K restage
    }

    float invl[4];
    #pragma unroll
    for (int i = 0; i < 4; ++i) invl[i] = 1.f / l_r[i];

    // ---------------- pass 2: normalized P -> attn + PV -> ctx ----------------
    float o[4][4] = {};
    const long abase = ((long)bh * S_LEN + qt * 64) * S_LEN;

    for (int kt = 0; kt < 32; ++kt) {
        if (kt > qt) {   // upper triangle: zeros (block-uniform branch)
            const float4 z = make_float4(0.f, 0.f, 0.f, 0.f);
            #pragma unroll
            for (int i = 0; i < 4; ++i)
                *(float4*)(attn + abase + (long)(4 * ty + i) * S_LEN + kt * 64 + 4 * tx) = z;
            continue;
        }
        const long kbase = ((long)bh * S_LEN + kt * 64) * HD;
        // stage K transposed
        #pragma unroll
        for (int it = 0; it < 4; ++it) {
            const int r = r0 + 16 * it;
            const float4 v = *(const float4*)(kT + kbase + (long)r * HD + c4 * 4);
            KVs[(c4 * 4 + 0) * PADW + r] = v.x;
            KVs[(c4 * 4 + 1) * PADW + r] = v.y;
            KVs[(c4 * 4 + 2) * PADW + r] = v.z;
            KVs[(c4 * 4 + 3) * PADW + r] = v.w;
        }
        __syncthreads();

        float acc[4][4] = {};
        #pragma unroll 8
        for (int d = 0; d < 64; ++d) {
            const float4 af = *(const float4*)(Qs + d * PADW + 4 * ty);
            const float4 bf = *(const float4*)(KVs + d * PADW + 4 * tx);
            const float a[4] = {af.x, af.y, af.z, af.w};
            const float b[4] = {bf.x, bf.y, bf.z, bf.w};
            #pragma unroll
            for (int i = 0; i < 4; ++i)
                #pragma unroll
                for (int j = 0; j < 4; ++j)
                    acc[i][j] += a[i] * b[j];
        }

        const bool diag = (kt == qt);
        #pragma unroll
        for (int i = 0; i < 4; ++i) {
            float p[4];
            #pragma unroll
            for (int j = 0; j < 4; ++j) {
                const float s = acc[i][j] * 0.125f;
                const bool msk = diag && (4 * tx + j) > (4 * ty + i);
                const float pp = msk ? 0.f : __expf(s - m_r[i]) * invl[i];
                p[j] = pp;
                Ps[(4 * tx + j) * PADW + 4 * ty + i] = pp;
            }
            *(float4*)(attn + abase + (long)(4 * ty + i) * S_LEN + kt * 64 + 4 * tx)
                = make_float4(p[0], p[1], p[2], p[3]);
        }
        __syncthreads();   // P visible; K-tile no longer needed

        // stage V (natural [kc][d] layout) into the shared K/V buffer
        #pragma unroll
        for (int it = 0; it < 4; ++it) {
            const int r = r0 + 16 * it;
            const float4 v = *(const float4*)(vT + kbase + (long)r * HD + c4 * 4);
            *(float4*)(KVs + r * PADW + c4 * 4) = v;
        }
        __syncthreads();

        #pragma unroll 8
        for (int kc = 0; kc < 64; ++kc) {
            const float4 af = *(const float4*)(Ps + kc * PADW + 4 * ty);
            const float4 bf = *(const float4*)(KVs + kc * PADW + 4 * tx);
            const float a[4] = {af.x, af.y, af.z, af.w};
            const float b[4] = {bf.x, bf.y, bf.z, bf.w};
            #pragma unroll
            for (int i = 0; i < 4; ++i)
                #pragma unroll
                for (int j = 0; j < 4; ++j)
                    o[i][j] += a[i] * b[j];
        }
        __syncthreads();   // before next restage
    }

    // write ctx [bh][s][d]
    #pragma unroll
    for (int i = 0; i < 4; ++i)
        *(float4*)(ctx + qbase + (long)(4 * ty + i) * HD + 4 * tx)
            = make_float4(o[i][0], o[i][1], o[i][2], o[i][3]);
}

// ---------------- launch ------------------------------------------------------
extern "C" void kernel_launch(void* const* d_in, const int* in_sizes, int n_in,
                              void* d_out, int out_size, void* d_ws, size_t ws_size,
                              hipStream_t stream) {
    const float* x    = (const float*)d_in[0];
    const float* Wq   = (const float*)d_in[1];
    const float* bq   = (const float*)d_in[2];
    const float* Wk   = (const float*)d_in[3];
    const float* bk   = (const float*)d_in[4];
    const float* Wv   = (const float*)d_in[5];
    const float* bv   = (const float*)d_in[6];
    const float* Wo   = (const float*)d_in[7];
    const float* bo   = (const float*)d_in[8];
    const float* cosp = (const float*)d_in[9];
    const float* sinp = (const float*)d_in[10];
    // d_in[11] = mask (causal tril) — implemented analytically.

    float* out = (float*)d_out;
    float* ws  = (float*)d_ws;

    float* qT  = ws;                 // fp32 [bh][s][d]
    float* kT  = ws + 4194304;
    float* vT  = ws + 8388608;
    float* ctx = ws + 12582912;

    float* hidden = out;
    float* attn   = out + (long)NROWS * DM;

    // Scratch for bf16 splits, parked in the (huge) attn output region.
    // All of it is consumed by the proj GEMMs BEFORE attn_tiled overwrites it.
    unsigned short* xh  = (unsigned short*)attn;
    unsigned short* xl  = xh  + 4194304;
    unsigned short* wqh = xl  + 4194304;
    unsigned short* wql = wqh + 1048576;
    unsigned short* wkh = wql + 1048576;
    unsigned short* wkl = wkh + 1048576;
    unsigned short* wvh = wkl + 1048576;
    unsigned short* wvl = wvh + 1048576;

    // Post-attn scratch: qT/kT are dead after attn_tiled -> reuse for ctx/Wo splits.
    unsigned short* cxh = (unsigned short*)ws;
    unsigned short* cxl = cxh + 4194304;
    unsigned short* woh = (unsigned short*)(ws + 4194304);
    unsigned short* wol = woh + 1048576;

    dim3 wgrid(16, 16);
    dim3 ggrid(16, 32);              // (N/64, M/128)

    split_kernel<<<2048, 256, 0, stream>>>(x, xh, xl, 1048576);
    wsplit_kernel<<<wgrid, 256, 0, stream>>>(Wq, wqh, wql);
    wsplit_kernel<<<wgrid, 256, 0, stream>>>(Wk, wkh, wkl);
    wsplit_kernel<<<wgrid, 256, 0, stream>>>(Wv, wvh, wvl);

    hipLaunchKernelGGL((mfma_gemm<0>), ggrid, dim3(256), 0, stream, xh, xl, wqh, wql, bq, cosp, sinp, qT);
    hipLaunchKernelGGL((mfma_gemm<0>), ggrid, dim3(256), 0, stream, xh, xl, wkh, wkl, bk, cosp, sinp, kT);
    hipLaunchKernelGGL((mfma_gemm<1>), ggrid, dim3(256), 0, stream, xh, xl, wvh, wvl, bv, cosp, sinp, vT);

    attn_tiled<<<NBATCH * NHEADS * 32, 256, 0, stream>>>(qT, kT, vT, attn, ctx);

    split_kernel<<<2048, 256, 0, stream>>>(ctx, cxh, cxl, 1048576);
    wsplit_kernel<<<wgrid, 256, 0, stream>>>(Wo, woh, wol);
    hipLaunchKernelGGL((mfma_gemm<2>), ggrid, dim3(256), 0, stream, cxh, cxl, woh, wol, bo, cosp, sinp, hidden);
}

// Round 2
// 921.776 us; speedup vs baseline: 1.5294x; 1.2126x over previous
//
#include <hip/hip_runtime.h>
#include <math.h>

#define S_LEN 2048
#define NBATCH 2
#define NHEADS 16
#define HD 64
#define DM 1024
#define NROWS (NBATCH * S_LEN)   // 4096

typedef __attribute__((ext_vector_type(8))) short bf16x8;
typedef __attribute__((ext_vector_type(4))) float f32x4;
typedef __attribute__((ext_vector_type(4))) unsigned short us4;

// ---------------- bf16 split helpers (round-to-nearest-even) -----------------
__device__ __forceinline__ unsigned short f2bf(float f) {
    unsigned int u = __float_as_uint(f);
    u += 0x7fffu + ((u >> 16) & 1u);
    return (unsigned short)(u >> 16);
}
__device__ __forceinline__ float bf2f(unsigned short h) {
    return __uint_as_float(((unsigned int)h) << 16);
}
__device__ __forceinline__ void split2(float v, unsigned short& h, unsigned short& l) {
    h = f2bf(v);
    l = f2bf(v - bf2f(h));
}

// ---------------- elementwise split (layout-preserving) ----------------------
__global__ __launch_bounds__(256)
void split_kernel(const float* __restrict__ src, unsigned short* __restrict__ hi,
                  unsigned short* __restrict__ lo, int n4) {
    for (long i = (long)blockIdx.x * 256 + threadIdx.x; i < n4; i += (long)gridDim.x * 256) {
        const float4 v = *(const float4*)(src + i * 4);
        unsigned short h0, h1, h2, h3, l0, l1, l2, l3;
        split2(v.x, h0, l0); split2(v.y, h1, l1);
        split2(v.z, h2, l2); split2(v.w, h3, l3);
        us4 H = {h0, h1, h2, h3}, L = {l0, l1, l2, l3};
        *(us4*)(hi + i * 4) = H;
        *(us4*)(lo + i * 4) = L;
    }
}

// ---------------- transpose + split: WT[n][k] = W[k][n] ----------------------
__global__ __launch_bounds__(256)
void wsplit_kernel(const float* __restrict__ W, unsigned short* __restrict__ hi,
                   unsigned short* __restrict__ lo) {
    __shared__ float T[64][65];
    const int c = threadIdx.x & 63, r0 = threadIdx.x >> 6;
    const int n0 = blockIdx.x * 64, k0 = blockIdx.y * 64;
    #pragma unroll
    for (int it = 0; it < 16; ++it) {
        const int r = r0 + it * 4;
        T[r][c] = W[(long)(k0 + r) * DM + n0 + c];
    }
    __syncthreads();
    #pragma unroll
    for (int it = 0; it < 16; ++it) {
        const int r = r0 + it * 4;                  // n-local
        unsigned short h, l;
        split2(T[c][r], h, l);
        hi[(long)(n0 + r) * DM + k0 + c] = h;
        lo[(long)(n0 + r) * DM + k0 + c] = l;
    }
}

// ---------------- bf16x3 MFMA GEMM ------------------------------------------
// C[4096][1024] = A @ B (+bias). B pre-transposed to [n][k]. Tile 128x64, BK=32.
// MODE 0: epilogue bias + RoPE -> split bf16 hi/lo, store [bh][s][d]   (q,k)
// MODE 1: epilogue bias        -> split bf16 hi/lo, store [bh][d][s]   (v, transposed)
// MODE 2: A = cx gathered bf16 [bh][s][d]; fp32 store (+bo)            (out proj)
#define SWZ(r) ((((r) & 3) ^ (((r) >> 2) & 3)))

template<int MODE>
__global__ __launch_bounds__(256)
void mfma_gemm(const unsigned short* __restrict__ Ah, const unsigned short* __restrict__ Al,
               const unsigned short* __restrict__ Bh, const unsigned short* __restrict__ Bl,
               const float* __restrict__ bias,
               const float* __restrict__ cosp, const float* __restrict__ sinp,
               unsigned short* __restrict__ outh, unsigned short* __restrict__ outl,
               float* __restrict__ outf)
{
    __shared__ __align__(16) unsigned short LAh[128 * 32];
    __shared__ __align__(16) unsigned short LAl[128 * 32];
    __shared__ __align__(16) unsigned short LBh[64 * 32];
    __shared__ __align__(16) unsigned short LBl[64 * 32];

    const int tid  = threadIdx.x;
    const int lane = tid & 63;
    const int wid  = tid >> 6;
    const int row0 = blockIdx.y * 128;
    const int col0 = blockIdx.x * 64;

    long aBase[2]; int aKoff[2]; int aDst[2];
    #pragma unroll
    for (int half = 0; half < 2; ++half) {
        const int c = tid + half * 256;
        const int r = c >> 2, b = c & 3;
        aDst[half] = r * 32 + ((b ^ SWZ(r)) << 3);
        if (MODE < 2) {
            aBase[half] = (long)(row0 + r) * DM + b * 8;
            aKoff[half] = 0;
        } else {
            const int gr = row0 + r;
            aBase[half] = ((long)((gr >> 11) * NHEADS) * S_LEN + (gr & (S_LEN - 1))) * HD;
            aKoff[half] = b * 8;
        }
    }
    const int rB = tid >> 2, bBlk = tid & 3;
    const long bBase = (long)(col0 + rB) * DM + bBlk * 8;
    const int  bDst  = rB * 32 + ((bBlk ^ SWZ(rB)) << 3);

    const int g = lane >> 4, lr = lane & 15;
    const int wr = (wid >> 1) * 64, wc = (wid & 1) * 32;
    int aoff[4], boff[2];
    #pragma unroll
    for (int mt = 0; mt < 4; ++mt) {
        const int rr = wr + mt * 16 + lr;
        aoff[mt] = rr * 32 + ((g ^ SWZ(rr)) << 3);
    }
    #pragma unroll
    for (int nt = 0; nt < 2; ++nt) {
        const int cc = wc + nt * 16 + lr;
        boff[nt] = cc * 32 + ((g ^ SWZ(cc)) << 3);
    }

    f32x4 acc[4][2];
    {
        const f32x4 z = {0.f, 0.f, 0.f, 0.f};
        #pragma unroll
        for (int mt = 0; mt < 4; ++mt)
            #pragma unroll
            for (int nt = 0; nt < 2; ++nt) acc[mt][nt] = z;
    }

    auto asrc_at = [&](int half, int kt) -> long {
        if (MODE < 2) return aBase[half] + kt;
        const int kk = kt + aKoff[half];
        return aBase[half] + (long)(kk >> 6) * (S_LEN * HD) + (kk & 63);
    };

    bf16x8 cA0h = *(const bf16x8*)(Ah + asrc_at(0, 0));
    bf16x8 cA0l = *(const bf16x8*)(Al + asrc_at(0, 0));
    bf16x8 cA1h = *(const bf16x8*)(Ah + asrc_at(1, 0));
    bf16x8 cA1l = *(const bf16x8*)(Al + asrc_at(1, 0));
    bf16x8 cB_h = *(const bf16x8*)(Bh + bBase);
    bf16x8 cB_l = *(const bf16x8*)(Bl + bBase);

    for (int kt = 0; kt < DM; kt += 32) {
        *(bf16x8*)(LAh + aDst[0]) = cA0h;
        *(bf16x8*)(LAl + aDst[0]) = cA0l;
        *(bf16x8*)(LAh + aDst[1]) = cA1h;
        *(bf16x8*)(LAl + aDst[1]) = cA1l;
        *(bf16x8*)(LBh + bDst) = cB_h;
        *(bf16x8*)(LBl + bDst) = cB_l;
        __syncthreads();

        const int kn = kt + 32;
        if (kn < DM) {
            cA0h = *(const bf16x8*)(Ah + asrc_at(0, kn));
            cA0l = *(const bf16x8*)(Al + asrc_at(0, kn));
            cA1h = *(const bf16x8*)(Ah + asrc_at(1, kn));
            cA1l = *(const bf16x8*)(Al + asrc_at(1, kn));
            cB_h = *(const bf16x8*)(Bh + bBase + kn);
            cB_l = *(const bf16x8*)(Bl + bBase + kn);
        }

        bf16x8 Bfh[2], Bfl[2];
        #pragma unroll
        for (int nt = 0; nt < 2; ++nt) {
            Bfh[nt] = *(const bf16x8*)(LBh + boff[nt]);
            Bfl[nt] = *(const bf16x8*)(LBl + boff[nt]);
        }
        #pragma unroll
        for (int mt = 0; mt < 4; ++mt) {
            const bf16x8 Afh = *(const bf16x8*)(LAh + aoff[mt]);
            const bf16x8 Afl = *(const bf16x8*)(LAl + aoff[mt]);
            #pragma unroll
            for (int nt = 0; nt < 2; ++nt) {
                acc[mt][nt] = __builtin_amdgcn_mfma_f32_16x16x32_bf16(Afh, Bfh[nt], acc[mt][nt], 0, 0, 0);
                acc[mt][nt] = __builtin_amdgcn_mfma_f32_16x16x32_bf16(Afh, Bfl[nt], acc[mt][nt], 0, 0, 0);
                acc[mt][nt] = __builtin_amdgcn_mfma_f32_16x16x32_bf16(Afl, Bfh[nt], acc[mt][nt], 0, 0, 0);
            }
        }
        __syncthreads();
    }

    // epilogue: C/D layout col = lane&15, row = (lane>>4)*4 + j
    #pragma unroll
    for (int mt = 0; mt < 4; ++mt) {
        #pragma unroll
        for (int nt = 0; nt < 2; ++nt) {
            const int colg = col0 + wc + nt * 16 + lr;
            const float bv = bias[colg];
            float vals[4];
            #pragma unroll
            for (int j = 0; j < 4; ++j) {
                const int rowg = row0 + wr + mt * 16 + g * 4 + j;
                float v = acc[mt][nt][j] + bv;
                if (MODE == 0) {
                    const int s  = rowg & (S_LEN - 1);
                    const int dd = colg & 63;
                    const int f = dd >> 1;
                    const float cs = cosp[s * 32 + f];
                    const float sn = sinp[s * 32 + f];
                    const float p  = __shfl_xor(v, 1);
                    v = (dd & 1) ? (p * sn + v * cs) : (v * cs - p * sn);
                }
                vals[j] = v;
            }
            const int rbase = row0 + wr + mt * 16 + g * 4;
            if (MODE == 2) {
                #pragma unroll
                for (int j = 0; j < 4; ++j)
                    outf[(long)(rbase + j) * DM + colg] = vals[j];
            } else {
                const int n = rbase >> 11;
                const int h = colg >> 6;
                const int dd = colg & 63;
                if (MODE == 0) {
                    #pragma unroll
                    for (int j = 0; j < 4; ++j) {
                        const int s = (rbase + j) & (S_LEN - 1);
                        const long addr = ((long)(n * NHEADS + h) * S_LEN + s) * HD + dd;
                        unsigned short hh, ll; split2(vals[j], hh, ll);
                        outh[addr] = hh; outl[addr] = ll;
                    }
                } else {   // MODE 1: [bh][d][s]
                    const int s0 = rbase & (S_LEN - 1);
                    unsigned short hh[4], ll[4];
                    #pragma unroll
                    for (int j = 0; j < 4; ++j) split2(vals[j], hh[j], ll[j]);
                    us4 H = {hh[0], hh[1], hh[2], hh[3]};
                    us4 L = {ll[0], ll[1], ll[2], ll[3]};
                    const long addr = ((long)((n * NHEADS + h) * HD + dd)) * S_LEN + s0;
                    *(us4*)(outh + addr) = H;
                    *(us4*)(outl + addr) = L;
                }
            }
        }
    }
}

// ---------------- MFMA flash attention (two-pass, bf16x3) --------------------
// Q/K: [bh][s][64] bf16 hi/lo.  V: [bh][64][s] bf16 hi/lo (transposed).
// Per block: one bh, one 64-query tile. 4 waves; wave w owns q-rows [16w,16w+16).
// LDS tiles [64][64] bf16, 16B-block XOR swizzle (blk ^= row&7) -> conflict-free
// b128 frag reads. P normalized in-register, written fp32 to attn output and
// bf16 hi/lo to LDS (same-wave consumption, no barrier needed).
__global__ __launch_bounds__(256)
void attn_mfma(const unsigned short* __restrict__ Qh, const unsigned short* __restrict__ Ql,
               const unsigned short* __restrict__ Kh, const unsigned short* __restrict__ Kl,
               const unsigned short* __restrict__ Vh, const unsigned short* __restrict__ Vl,
               float* __restrict__ attn,
               unsigned short* __restrict__ cxh, unsigned short* __restrict__ cxl)
{
    __shared__ __align__(16) unsigned short sQh[4096], sQl[4096];
    __shared__ __align__(16) unsigned short sKh[4096], sKl[4096];
    __shared__ __align__(16) unsigned short sVh[4096], sVl[4096];
    __shared__ __align__(16) unsigned short sPh[4096], sPl[4096];

    const int bh  = blockIdx.x & 31;
    const int qt  = 31 - (blockIdx.x >> 5);   // biggest tiles first
    const int tid = threadIdx.x;
    const int lane = tid & 63, wid = tid >> 6;
    const int g = lane >> 4, lr = lane & 15;
    const int wrow = wid << 4;

    // staging chunks: 512 16B chunks per [64][64] tile, 2 per thread
    int sRow[2], sBlk[2], sDst[2];
    #pragma unroll
    for (int h = 0; h < 2; ++h) {
        const int c = tid + h * 256;
        sRow[h] = c >> 3; sBlk[h] = c & 7;
        sDst[h] = sRow[h] * 64 + ((sBlk[h] ^ (sRow[h] & 7)) << 3);
    }

    // stage Q (once)
    #pragma unroll
    for (int h = 0; h < 2; ++h) {
        const long src = ((long)bh * S_LEN + qt * 64 + sRow[h]) * HD + sBlk[h] * 8;
        *(bf16x8*)(sQh + sDst[h]) = *(const bf16x8*)(Qh + src);
        *(bf16x8*)(sQl + sDst[h]) = *(const bf16x8*)(Ql + src);
    }

    // fragment offsets (rows of a [64][64] swizzled tile)
    int aoff[2], boff[4][2];
    {
        const int ar = wrow + lr;
        #pragma unroll
        for (int ks = 0; ks < 2; ++ks)
            aoff[ks] = ar * 64 + ((((ks << 2) | g) ^ (ar & 7)) << 3);
        #pragma unroll
        for (int nt = 0; nt < 4; ++nt) {
            const int br = nt * 16 + lr;
            #pragma unroll
            for (int ks = 0; ks < 2; ++ks)
                boff[nt][ks] = br * 64 + ((((ks << 2) | g) ^ (br & 7)) << 3);
        }
    }

    float m_r[4], l_r[4];
    #pragma unroll
    for (int j = 0; j < 4; ++j) { m_r[j] = -1e30f; l_r[j] = 0.f; }

    // ---------------- pass 1: online row max & sum ----------------
    for (int kt = 0; kt <= qt; ++kt) {
        __syncthreads();
        #pragma unroll
        for (int h = 0; h < 2; ++h) {
            const long src = ((long)bh * S_LEN + kt * 64 + sRow[h]) * HD + sBlk[h] * 8;
            *(bf16x8*)(sKh + sDst[h]) = *(const bf16x8*)(Kh + src);
            *(bf16x8*)(sKl + sDst[h]) = *(const bf16x8*)(Kl + src);
        }
        __syncthreads();

        f32x4 acc[4];
        { const f32x4 z = {0.f,0.f,0.f,0.f};
          #pragma unroll
          for (int nt = 0; nt < 4; ++nt) acc[nt] = z; }
        #pragma unroll
        for (int ks = 0; ks < 2; ++ks) {
            const bf16x8 ah = *(const bf16x8*)(sQh + aoff[ks]);
            const bf16x8 al = *(const bf16x8*)(sQl + aoff[ks]);
            #pragma unroll
            for (int nt = 0; nt < 4; ++nt) {
                const bf16x8 bhf = *(const bf16x8*)(sKh + boff[nt][ks]);
                const bf16x8 blf = *(const bf16x8*)(sKl + boff[nt][ks]);
                acc[nt] = __builtin_amdgcn_mfma_f32_16x16x32_bf16(ah, bhf, acc[nt], 0, 0, 0);
                acc[nt] = __builtin_amdgcn_mfma_f32_16x16x32_bf16(ah, blf, acc[nt], 0, 0, 0);
                acc[nt] = __builtin_amdgcn_mfma_f32_16x16x32_bf16(al, bhf, acc[nt], 0, 0, 0);
            }
        }

        const bool diag = (kt == qt);
        #pragma unroll
        for (int j = 0; j < 4; ++j) {
            const int qlcl = wrow + g * 4 + j;
            float sv[4]; float tmax = -1e30f;
            #pragma unroll
            for (int nt = 0; nt < 4; ++nt) {
                float s = acc[nt][j] * 0.125f;
                if (diag && (nt * 16 + lr) > qlcl) s = -1e30f;
                sv[nt] = s; tmax = fmaxf(tmax, s);
            }
            #pragma unroll
            for (int off = 1; off < 16; off <<= 1)
                tmax = fmaxf(tmax, __shfl_xor(tmax, off));
            const float mn = fmaxf(m_r[j], tmax);
            float ps = 0.f;
            #pragma unroll
            for (int nt = 0; nt < 4; ++nt) ps += __expf(sv[nt] - mn);
            #pragma unroll
            for (int off = 1; off < 16; off <<= 1)
                ps += __shfl_xor(ps, off);
            l_r[j] = l_r[j] * __expf(m_r[j] - mn) + ps;
            m_r[j] = mn;
        }
    }

    float invl[4];
    #pragma unroll
    for (int j = 0; j < 4; ++j) invl[j] = 1.f / l_r[j];

    // ---------------- pass 2: P -> attn + PV -> ctx ----------------
    f32x4 oacc[4];
    { const f32x4 z = {0.f,0.f,0.f,0.f};
      #pragma unroll
      for (int nt = 0; nt < 4; ++nt) oacc[nt] = z; }
    const long abase = ((long)bh * S_LEN + qt * 64) * S_LEN;

    for (int kt = 0; kt <= qt; ++kt) {
        __syncthreads();
        #pragma unroll
        for (int h = 0; h < 2; ++h) {
            const long srck = ((long)bh * S_LEN + kt * 64 + sRow[h]) * HD + sBlk[h] * 8;
            const long srcv = ((long)(bh * HD + sRow[h])) * S_LEN + kt * 64 + sBlk[h] * 8;
            *(bf16x8*)(sKh + sDst[h]) = *(const bf16x8*)(Kh + srck);
            *(bf16x8*)(sKl + sDst[h]) = *(const bf16x8*)(Kl + srck);
            *(bf16x8*)(sVh + sDst[h]) = *(const bf16x8*)(Vh + srcv);
            *(bf16x8*)(sVl + sDst[h]) = *(const bf16x8*)(Vl + srcv);
        }
        __syncthreads();

        f32x4 acc[4];
        { const f32x4 z = {0.f,0.f,0.f,0.f};
          #pragma unroll
          for (int nt = 0; nt < 4; ++nt) acc[nt] = z; }
        #pragma unroll
        for (int ks = 0; ks < 2; ++ks) {
            const bf16x8 ah = *(const bf16x8*)(sQh + aoff[ks]);
            const bf16x8 al = *(const bf16x8*)(sQl + aoff[ks]);
            #pragma unroll
            for (int nt = 0; nt < 4; ++nt) {
                const bf16x8 bhf = *(const bf16x8*)(sKh + boff[nt][ks]);
                const bf16x8 blf = *(const bf16x8*)(sKl + boff[nt][ks]);
                acc[nt] = __builtin_amdgcn_mfma_f32_16x16x32_bf16(ah, bhf, acc[nt], 0, 0, 0);
                acc[nt] = __builtin_amdgcn_mfma_f32_16x16x32_bf16(ah, blf, acc[nt], 0, 0, 0);
                acc[nt] = __builtin_amdgcn_mfma_f32_16x16x32_bf16(al, bhf, acc[nt], 0, 0, 0);
            }
        }

        const bool diag = (kt == qt);
        #pragma unroll
        for (int j = 0; j < 4; ++j) {
            const int qlcl = wrow + g * 4 + j;
            #pragma unroll
            for (int nt = 0; nt < 4; ++nt) {
                const int kk = nt * 16 + lr;
                const float s = acc[nt][j] * 0.125f;
                const bool msk = diag && kk > qlcl;
                const float p = msk ? 0.f : __expf(s - m_r[j]) * invl[j];
                attn[abase + (long)qlcl * S_LEN + kt * 64 + kk] = p;
                unsigned short ph_, pl_; split2(p, ph_, pl_);
                const int pb = kk >> 3;
                const int paddr = qlcl * 64 + ((pb ^ (qlcl & 7)) << 3) + (kk & 7);
                sPh[paddr] = ph_; sPl[paddr] = pl_;
            }
        }

        // PV — P rows consumed by the wave that wrote them (no barrier needed)
        #pragma unroll
        for (int ks = 0; ks < 2; ++ks) {
            const bf16x8 pah = *(const bf16x8*)(sPh + aoff[ks]);
            const bf16x8 pal = *(const bf16x8*)(sPl + aoff[ks]);
            #pragma unroll
            for (int nt = 0; nt < 4; ++nt) {
                const bf16x8 vhf = *(const bf16x8*)(sVh + boff[nt][ks]);
                const bf16x8 vlf = *(const bf16x8*)(sVl + boff[nt][ks]);
                oacc[nt] = __builtin_amdgcn_mfma_f32_16x16x32_bf16(pah, vhf, oacc[nt], 0, 0, 0);
                oacc[nt] = __builtin_amdgcn_mfma_f32_16x16x32_bf16(pah, vlf, oacc[nt], 0, 0, 0);
                oacc[nt] = __builtin_amdgcn_mfma_f32_16x16x32_bf16(pal, vhf, oacc[nt], 0, 0, 0);
            }
        }
    }

    // zero upper-triangle attn tiles
    {
        const int zc0 = (qt + 1) * 64;
        const int r = tid >> 2;
        const float4 z = make_float4(0.f, 0.f, 0.f, 0.f);
        for (int c = zc0 + (tid & 3) * 4; c < S_LEN; c += 16)
            *(float4*)(attn + abase + (long)r * S_LEN + c) = z;
    }

    // write ctx as bf16 hi/lo [bh][s][d] (feeds out-proj GEMM directly)
    #pragma unroll
    for (int nt = 0; nt < 4; ++nt) {
        #pragma unroll
        for (int j = 0; j < 4; ++j) {
            const int qlcl = wrow + g * 4 + j;
            const long caddr = ((long)bh * S_LEN + qt * 64 + qlcl) * HD + nt * 16 + lr;
            unsigned short hh, ll; split2(oacc[nt][j], hh, ll);
            cxh[caddr] = hh; cxl[caddr] = ll;
        }
    }
}

// ---------------- launch ------------------------------------------------------
extern "C" void kernel_launch(void* const* d_in, const int* in_sizes, int n_in,
                              void* d_out, int out_size, void* d_ws, size_t ws_size,
                              hipStream_t stream) {
    (void)in_sizes; (void)n_in; (void)out_size; (void)ws_size;
    const float* x    = (const float*)d_in[0];
    const float* Wq   = (const float*)d_in[1];
    const float* bq   = (const float*)d_in[2];
    const float* Wk   = (const float*)d_in[3];
    const float* bk   = (const float*)d_in[4];
    const float* Wv   = (const float*)d_in[5];
    const float* bv   = (const float*)d_in[6];
    const float* Wo   = (const float*)d_in[7];
    const float* bo   = (const float*)d_in[8];
    const float* cosp = (const float*)d_in[9];
    const float* sinp = (const float*)d_in[10];
    // d_in[11] = mask — analytic.

    float* out = (float*)d_out;
    float* hidden = out;
    float* attn   = out + (long)NROWS * DM;

    // ws (64 MB) holds the bf16 attn operands + ctx splits
    unsigned short* wsu = (unsigned short*)d_ws;
    unsigned short* qh_ = wsu;                    // 8 MB each (4194304 u16)
    unsigned short* ql_ = wsu + 4194304;
    unsigned short* kh_ = wsu + 8388608;
    unsigned short* kl_ = wsu + 12582912;
    unsigned short* vth = wsu + 16777216;
    unsigned short* vtl = wsu + 20971520;
    unsigned short* cxh = wsu + 25165824;
    unsigned short* cxl = wsu + 29360128;

    // pre-attn scratch parked in the attn output region (dead until attn runs)
    unsigned short* xh  = (unsigned short*)attn;
    unsigned short* xl  = xh  + 4194304;
    unsigned short* wqh = xl  + 4194304;
    unsigned short* wql = wqh + 1048576;
    unsigned short* wkh = wql + 1048576;
    unsigned short* wkl = wkh + 1048576;
    unsigned short* wvh = wkl + 1048576;
    unsigned short* wvl = wvh + 1048576;

    // post-attn scratch: q/k splits dead after attn -> reuse for Wo split
    unsigned short* woh = qh_;
    unsigned short* wol = qh_ + 1048576;

    dim3 wgrid(16, 16);
    dim3 ggrid(16, 32);              // (N/64, M/128)

    split_kernel<<<2048, 256, 0, stream>>>(x, xh, xl, 1048576);
    wsplit_kernel<<<wgrid, 256, 0, stream>>>(Wq, wqh, wql);
    wsplit_kernel<<<wgrid, 256, 0, stream>>>(Wk, wkh, wkl);
    wsplit_kernel<<<wgrid, 256, 0, stream>>>(Wv, wvh, wvl);

    hipLaunchKernelGGL((mfma_gemm<0>), ggrid, dim3(256), 0, stream,
                       xh, xl, wqh, wql, bq, cosp, sinp, qh_, ql_, (float*)nullptr);
    hipLaunchKernelGGL((mfma_gemm<0>), ggrid, dim3(256), 0, stream,
                       xh, xl, wkh, wkl, bk, cosp, sinp, kh_, kl_, (float*)nullptr);
    hipLaunchKernelGGL((mfma_gemm<1>), ggrid, dim3(256), 0, stream,
                       xh, xl, wvh, wvl, bv, cosp, sinp, vth, vtl, (float*)nullptr);

    attn_mfma<<<NBATCH * NHEADS * 32, 256, 0, stream>>>(qh_, ql_, kh_, kl_, vth, vtl,
                                                        attn, cxh, cxl);

    wsplit_kernel<<<wgrid, 256, 0, stream>>>(Wo, woh, wol);
    hipLaunchKernelGGL((mfma_gemm<2>), ggrid, dim3(256), 0, stream,
                       cxh, cxl, woh, wol, bo, cosp, sinp,
                       (unsigned short*)nullptr, (unsigned short*)nullptr, hidden);
}